// Round 5
// baseline (803.388 us; speedup 1.0000x reference)
//
#include <hip/hip_runtime.h>
#include <hip/hip_bf16.h>
#include <stdint.h>

#define D_DIM 256
#define INV_T 14.285714285714286f  // 1/0.07

#define BM 256
#define BN 256
#define BK 32
#define NSTEP (D_DIM / BK)  // 8

typedef __bf16 bf16x8 __attribute__((ext_vector_type(8)));
typedef float f32x16 __attribute__((ext_vector_type(16)));

// ---------------------------------------------------------------------------
// Kernel A: normalization. One wave per row (float4 loads), 4 rows/block.
// Exact fp32 diagonal Sv, bf16 normalized outputs, rowsum & done zero-init.
// ---------------------------------------------------------------------------
__global__ __launch_bounds__(256) void lit_normalize(
    const float* __restrict__ X, const float* __restrict__ Y,
    __hip_bfloat16* __restrict__ Xb, __hip_bfloat16* __restrict__ Yb,
    float* __restrict__ Sv, float* __restrict__ rowsum, unsigned* __restrict__ done)
{
    const int l = threadIdx.x & 63;
    const int row = blockIdx.x * 4 + (threadIdx.x >> 6);
    const size_t base = (size_t)row * D_DIM;
    const float4 x = ((const float4*)(X + base))[l];
    const float4 y = ((const float4*)(Y + base))[l];
    float nx = x.x * x.x + x.y * x.y + x.z * x.z + x.w * x.w;
    float ny = y.x * y.x + y.y * y.y + y.z * y.z + y.w * y.w;
    float dt = x.x * y.x + x.y * y.y + x.z * y.z + x.w * y.w;
    #pragma unroll
    for (int o = 1; o < 64; o <<= 1) {
        nx += __shfl_xor(nx, o);
        ny += __shfl_xor(ny, o);
        dt += __shfl_xor(dt, o);
    }
    const float ivx = 1.0f / fmaxf(sqrtf(nx), 1e-12f);
    const float ivy = 1.0f / fmaxf(sqrtf(ny), 1e-12f);

    __hip_bfloat16 hx0 = __float2bfloat16(x.x * ivx), hx1 = __float2bfloat16(x.y * ivx);
    __hip_bfloat16 hx2 = __float2bfloat16(x.z * ivx), hx3 = __float2bfloat16(x.w * ivx);
    __hip_bfloat16 hy0 = __float2bfloat16(y.x * ivy), hy1 = __float2bfloat16(y.y * ivy);
    __hip_bfloat16 hy2 = __float2bfloat16(y.z * ivy), hy3 = __float2bfloat16(y.w * ivy);
    ushort4 px, py;
    px.x = *(unsigned short*)&hx0; px.y = *(unsigned short*)&hx1;
    px.z = *(unsigned short*)&hx2; px.w = *(unsigned short*)&hx3;
    py.x = *(unsigned short*)&hy0; py.y = *(unsigned short*)&hy1;
    py.z = *(unsigned short*)&hy2; py.w = *(unsigned short*)&hy3;
    ((ushort4*)(Xb + base))[l] = px;
    ((ushort4*)(Yb + base))[l] = py;

    if (l == 0) {
        Sv[row] = (dt * ivx * ivy - 1.0f) * INV_T;  // exact diagonal logit
        rowsum[row] = 0.0f;
    }
    if (blockIdx.x == 0 && threadIdx.x == 0) done[0] = 0u;
}

// ---------------------------------------------------------------------------
// Kernel B: S = Xhat @ Yhat^T with swapped operands (D = mfma(Yf, Xf), so
// D[m=j][n=i] -> j-reduction is in-thread), fused exp/rowsum epilogue and
// last-block finalize.
// 256x256 tile, BK=32, 8 waves (wi=w>>2: 2 i-halves of 128; wj=w&3: 4
// j-quarters of 64). 32x32x16 bf16 MFMA; acc[fj:2][fi:4].
// Pipeline (compiler-friendly dbuf, ONE __syncthreads per K-step):
//   ds_read cur-buf fragments -> regs; issue STAGE(next buf);
//   MFMAs; __syncthreads().
// The compiler's vmcnt(0)+lgkmcnt(0) drain before the barrier lands AFTER the
// MFMA cluster, so the next tile's load latency hides under compute. No
// inline asm / sched_barrier / raw barriers (round-4 lesson, m141 pathology).
// LDS swizzle: physical 16B slot = g ^ ((row>>1)&3), realized on the write
// side by pre-swizzling the global source (global_load_lds dest stays linear).
// ---------------------------------------------------------------------------
__global__ __launch_bounds__(512, 2) void lit_gemm_rowsum(
    const __hip_bfloat16* __restrict__ Xb, const __hip_bfloat16* __restrict__ Yb,
    const float* __restrict__ Sv, float* __restrict__ rowsum,
    unsigned* __restrict__ done, float* __restrict__ out, int N)
{
    __shared__ char lds[2 * 32768];  // [buf][X 16KB | Y 16KB]

    const int tid = (int)threadIdx.x;
    const int l   = tid & 63;
    const int w   = tid >> 6;    // 0..7
    const int wi  = w >> 2;      // 0..1  (i-half: 128 rows)
    const int wj  = w & 3;       // 0..3  (j-quarter: 64 rows)

    // XCD-aware bijective swizzle (nwg = 4096, %8 == 0)
    const int nx  = (int)gridDim.x;
    const int bid = (int)blockIdx.y * nx + (int)blockIdx.x;
    const int cpx = (nx * (int)gridDim.y) >> 3;
    const int logical = (bid & 7) * cpx + (bid >> 3);
    const int bi = logical / nx;
    const int bj = logical % nx;
    const int iBase = bi * BM;
    const int jBase = bj * BN;

    f32x16 acc[2][4];
    #pragma unroll
    for (int a = 0; a < 2; ++a)
        #pragma unroll
        for (int b = 0; b < 4; ++b)
            #pragma unroll
            for (int r = 0; r < 16; ++r)
                acc[a][b][r] = 0.f;

    // Staging: 32 chunks of 16 rows x 64B = 1KB; wave w owns chunks w*4..w*4+3.
    // Chunks 0..15 = X rows 0..255; chunks 16..31 = Y rows 0..255.
    const int rq = l >> 2;   // row within chunk
    const int sl = l & 3;    // 16B slot within a 64B row
    const char* src[4];
    int dst[4];
    #pragma unroll
    for (int c = 0; c < 4; ++c) {
        const int g    = w * 4 + c;
        const int isY  = g >> 4;
        const int r16  = (g & 15) * 16;
        const int row  = r16 + rq;
        const int slot = sl ^ ((row >> 1) & 3);  // pre-swizzled source slot
        const char* base = isY ? (const char*)Yb + (size_t)jBase * (D_DIM * 2)
                               : (const char*)Xb + (size_t)iBase * (D_DIM * 2);
        src[c] = base + (size_t)row * (D_DIM * 2) + slot * 16;
        dst[c] = isY * 16384 + r16 * 64;
    }

#define STAGE(buf, t)                                                              \
    {                                                                              \
        _Pragma("unroll")                                                          \
        for (int c = 0; c < 4; ++c)                                                \
            __builtin_amdgcn_global_load_lds(                                      \
                (const __attribute__((address_space(1))) void*)(src[c] + (t) * (BK * 2)), \
                (__attribute__((address_space(3))) void*)(lds + (buf) * 32768 + dst[c]),  \
                16, 0, 0);                                                         \
    }

    STAGE(0, 0);
    __syncthreads();   // buf0 staged (compiler drains vmcnt before barrier)

    #pragma unroll
    for (int t = 0; t < NSTEP; ++t) {
        const char* Xs = lds + (t & 1) * 32768;
        const char* Ys = Xs + 16384;
        const int lr = l & 31;

        // 1) read this tile's fragments into registers (all compile-time idx)
        bf16x8 af[2][2], bg[2][4];
        #pragma unroll
        for (int kk = 0; kk < 2; ++kk) {
            // logical 16B k-slot g = kk*2 + (l>>5); physical = g ^ ((row>>1)&3)
            const int sx = ((kk * 2 + (l >> 5)) ^ ((l >> 1) & 3)) * 16;
            af[kk][0] = *(const bf16x8*)(Ys + (wj * 64 +  0 + lr) * 64 + sx);
            af[kk][1] = *(const bf16x8*)(Ys + (wj * 64 + 32 + lr) * 64 + sx);
            bg[kk][0] = *(const bf16x8*)(Xs + (wi * 128 +  0 + lr) * 64 + sx);
            bg[kk][1] = *(const bf16x8*)(Xs + (wi * 128 + 32 + lr) * 64 + sx);
            bg[kk][2] = *(const bf16x8*)(Xs + (wi * 128 + 64 + lr) * 64 + sx);
            bg[kk][3] = *(const bf16x8*)(Xs + (wi * 128 + 96 + lr) * 64 + sx);
        }

        // 2) prefetch next K-tile into the other buffer (latency hidden by 3)
        if (t < NSTEP - 1) STAGE((t + 1) & 1, t + 1);

        // 3) MFMA cluster
        #pragma unroll
        for (int kk = 0; kk < 2; ++kk) {
            acc[0][0] = __builtin_amdgcn_mfma_f32_32x32x16_bf16(af[kk][0], bg[kk][0], acc[0][0], 0, 0, 0);
            acc[0][1] = __builtin_amdgcn_mfma_f32_32x32x16_bf16(af[kk][0], bg[kk][1], acc[0][1], 0, 0, 0);
            acc[0][2] = __builtin_amdgcn_mfma_f32_32x32x16_bf16(af[kk][0], bg[kk][2], acc[0][2], 0, 0, 0);
            acc[0][3] = __builtin_amdgcn_mfma_f32_32x32x16_bf16(af[kk][0], bg[kk][3], acc[0][3], 0, 0, 0);
            acc[1][0] = __builtin_amdgcn_mfma_f32_32x32x16_bf16(af[kk][1], bg[kk][0], acc[1][0], 0, 0, 0);
            acc[1][1] = __builtin_amdgcn_mfma_f32_32x32x16_bf16(af[kk][1], bg[kk][1], acc[1][1], 0, 0, 0);
            acc[1][2] = __builtin_amdgcn_mfma_f32_32x32x16_bf16(af[kk][1], bg[kk][2], acc[1][2], 0, 0, 0);
            acc[1][3] = __builtin_amdgcn_mfma_f32_32x32x16_bf16(af[kk][1], bg[kk][3], acc[1][3], 0, 0, 0);
        }

        // 4) single rendezvous: reads of buf[t&1] done + stage(t+1) drained
        __syncthreads();
    }

    // ---- epilogue: rowsum_i += sum_j exp((S[i][j]-1)/tau) ----
    // D layout (32x32): n=i = lane&31; m=j = (reg&3)+8*(reg>>2)+4*(lane>>5).
    float part[4];
    #pragma unroll
    for (int fi = 0; fi < 4; ++fi) {
        float s = 0.f;
        #pragma unroll
        for (int fj = 0; fj < 2; ++fj)
            #pragma unroll
            for (int r = 0; r < 16; ++r)
                s += __expf(fmaf(acc[fj][fi][r], INV_T, -INV_T));
        s += __shfl_xor(s, 32);
        part[fi] = s;
    }
    float* rowpart = (float*)lds;
    if (tid < BM) rowpart[tid] = 0.f;
    __syncthreads();
    if (l < 32) {
        #pragma unroll
        for (int fi = 0; fi < 4; ++fi)
            atomicAdd(&rowpart[wi * 128 + fi * 32 + l], part[fi]);
    }
    __syncthreads();
    if (tid < BM) atomicAdd(&rowsum[iBase + tid], rowpart[tid]);

    // ---- fused finalize: last block computes -mean(Sv - log(rowsum)) ----
    __threadfence();   // order rowsum atomics before the counter increment
    __syncthreads();
    __shared__ unsigned lastBlock;
    if (tid == 0) {
        unsigned old = atomicAdd(done, 1u);
        lastBlock = (old == (unsigned)(gridDim.x * gridDim.y) - 1u) ? 1u : 0u;
        if (lastBlock) __threadfence();  // acquire: rowsum atomics from all blocks
    }
    __syncthreads();
    if (lastBlock) {
        float s = 0.f;
        for (int r = tid; r < N; r += 512) {
            float rs = __hip_atomic_load(&rowsum[r], __ATOMIC_RELAXED, __HIP_MEMORY_SCOPE_AGENT);
            s += Sv[r] - __logf(rs);
        }
        #pragma unroll
        for (int o = 1; o < 64; o <<= 1) s += __shfl_xor(s, o);
        __shared__ float fr[8];
        if ((tid & 63) == 0) fr[tid >> 6] = s;
        __syncthreads();
        if (tid == 0) {
            float tot = 0.f;
            #pragma unroll
            for (int k = 0; k < 8; ++k) tot += fr[k];
            out[0] = -tot / (float)N;
        }
    }
}

// ---------------------------------------------------------------------------
extern "C" void kernel_launch(void* const* d_in, const int* in_sizes, int n_in,
                              void* d_out, int out_size, void* d_ws, size_t ws_size,
                              hipStream_t stream)
{
    const float* X = (const float*)d_in[0];
    const float* Y = (const float*)d_in[1];
    const int N = in_sizes[0] / D_DIM;  // 16384

    char* ws = (char*)d_ws;
    __hip_bfloat16* Xb = (__hip_bfloat16*)ws;
    __hip_bfloat16* Yb = (__hip_bfloat16*)(ws + (size_t)N * D_DIM * 2);
    float* Sv       = (float*)(ws + (size_t)N * D_DIM * 4);
    float* rowsum   = (float*)(ws + (size_t)N * D_DIM * 4 + (size_t)N * 4);
    unsigned* done  = (unsigned*)(ws + (size_t)N * D_DIM * 4 + (size_t)N * 8);

    lit_normalize<<<N / 4, 256, 0, stream>>>(X, Y, Xb, Yb, Sv, rowsum, done);
    dim3 grid(N / BN, N / BM);
    lit_gemm_rowsum<<<grid, 512, 0, stream>>>(Xb, Yb, Sv, rowsum, done, (float*)d_out, N);
}

// Round 6
// 244.103 us; speedup vs baseline: 3.2912x; 3.2912x over previous
//
#include <hip/hip_runtime.h>
#include <hip/hip_bf16.h>
#include <stdint.h>

#define D_DIM 256
#define INV_T 14.285714285714286f  // 1/0.07

#define BM 256
#define BN 256
#define BK 64
#define NSTEP (D_DIM / BK)  // 4

typedef __bf16 bf16x8 __attribute__((ext_vector_type(8)));
typedef float f32x16 __attribute__((ext_vector_type(16)));

// ---------------------------------------------------------------------------
// Kernel A: normalization. One wave per row (float4 loads), 4 rows/block.
// Exact fp32 diagonal Sv, bf16 normalized outputs, rowsum & acc1 zero-init.
// ---------------------------------------------------------------------------
__global__ __launch_bounds__(256) void lit_normalize(
    const float* __restrict__ X, const float* __restrict__ Y,
    __hip_bfloat16* __restrict__ Xb, __hip_bfloat16* __restrict__ Yb,
    float* __restrict__ Sv, float* __restrict__ rowsum, float* __restrict__ acc1)
{
    const int l = threadIdx.x & 63;
    const int row = blockIdx.x * 4 + (threadIdx.x >> 6);
    const size_t base = (size_t)row * D_DIM;
    const float4 x = ((const float4*)(X + base))[l];
    const float4 y = ((const float4*)(Y + base))[l];
    float nx = x.x * x.x + x.y * x.y + x.z * x.z + x.w * x.w;
    float ny = y.x * y.x + y.y * y.y + y.z * y.z + y.w * y.w;
    float dt = x.x * y.x + x.y * y.y + x.z * y.z + x.w * y.w;
    #pragma unroll
    for (int o = 1; o < 64; o <<= 1) {
        nx += __shfl_xor(nx, o);
        ny += __shfl_xor(ny, o);
        dt += __shfl_xor(dt, o);
    }
    const float ivx = 1.0f / fmaxf(sqrtf(nx), 1e-12f);
    const float ivy = 1.0f / fmaxf(sqrtf(ny), 1e-12f);

    __hip_bfloat16 hx0 = __float2bfloat16(x.x * ivx), hx1 = __float2bfloat16(x.y * ivx);
    __hip_bfloat16 hx2 = __float2bfloat16(x.z * ivx), hx3 = __float2bfloat16(x.w * ivx);
    __hip_bfloat16 hy0 = __float2bfloat16(y.x * ivy), hy1 = __float2bfloat16(y.y * ivy);
    __hip_bfloat16 hy2 = __float2bfloat16(y.z * ivy), hy3 = __float2bfloat16(y.w * ivy);
    ushort4 px, py;
    px.x = *(unsigned short*)&hx0; px.y = *(unsigned short*)&hx1;
    px.z = *(unsigned short*)&hx2; px.w = *(unsigned short*)&hx3;
    py.x = *(unsigned short*)&hy0; py.y = *(unsigned short*)&hy1;
    py.z = *(unsigned short*)&hy2; py.w = *(unsigned short*)&hy3;
    ((ushort4*)(Xb + base))[l] = px;
    ((ushort4*)(Yb + base))[l] = py;

    if (l == 0) {
        Sv[row] = (dt * ivx * ivy - 1.0f) * INV_T;  // exact diagonal logit
        rowsum[row] = 0.0f;
    }
    if (blockIdx.x == 0 && threadIdx.x == 0) acc1[0] = 0.0f;
}

// ---------------------------------------------------------------------------
// Kernel B: S = Xhat @ Yhat^T with SWAPPED operands (D = mfma(Yf, Xf), so
// D[m=j][n=i] -> j-reduction is in-thread). Round-2 proven structure:
// 256x256 tile, BK=64, single 64KB LDS buffer, 2 __syncthreads per K-step,
// 8 waves (wi=w>>2: 2 i-halves of 128; wj=w&3: 4 j-quarters of 64),
// 32x32x16 bf16 MFMA, acc[fj:2][fi:4].
// LDS swizzle: physical 16B slot = g ^ (row&7), realized on the write side by
// pre-swizzling the global source (global_load_lds dest stays linear; rule #21).
// NO __threadfence / fused finalize (round-5 lesson: per-block agent fences
// cause L2 writeback storms on multi-XCD -> 3.5x regression).
// Epilogue: conflict-free per-wave rowpart slots (plain stores), no LDS atomics
// (round-5 lesson: SQ_LDS_BANK_CONFLICT 1.26e7 was the epilogue atomics).
// ---------------------------------------------------------------------------
__global__ __launch_bounds__(512, 2) void lit_gemm_rowsum(
    const __hip_bfloat16* __restrict__ Xb, const __hip_bfloat16* __restrict__ Yb,
    float* __restrict__ rowsum)
{
    __shared__ char lds[BM * BK * 2 + BN * BK * 2];  // 32KB Xs + 32KB Ys

    const int tid = (int)threadIdx.x;
    const int l   = tid & 63;
    const int w   = tid >> 6;    // 0..7
    const int wi  = w >> 2;      // 0..1  (i-half: 128 rows)
    const int wj  = w & 3;       // 0..3  (j-quarter: 64 rows)

    // XCD-aware bijective swizzle (nwg = 4096, %8 == 0)
    const int nx  = (int)gridDim.x;
    const int bid = (int)blockIdx.y * nx + (int)blockIdx.x;
    const int cpx = (nx * (int)gridDim.y) >> 3;
    const int logical = (bid & 7) * cpx + (bid >> 3);
    const int bi = logical / nx;
    const int bj = logical % nx;
    const int iBase = bi * BM;
    const int jBase = bj * BN;

    f32x16 acc[2][4];
    #pragma unroll
    for (int a = 0; a < 2; ++a)
        #pragma unroll
        for (int b = 0; b < 4; ++b)
            #pragma unroll
            for (int r = 0; r < 16; ++r)
                acc[a][b][r] = 0.f;

    // Staging: 64 chunks of 8 rows x 128B = 1KB; wave w owns chunks w*8..w*8+7.
    // Chunks 0..31 = X rows 0..255; chunks 32..63 = Y rows 0..255.
    const int rq = l >> 3;   // row within chunk
    const int sl = l & 7;    // 16B slot within a 128B row
    const char* src[8];
    int dst[8];
    #pragma unroll
    for (int c = 0; c < 8; ++c) {
        const int g    = w * 8 + c;
        const int isY  = g >> 5;
        const int r8   = (g & 31) * 8;
        const int row  = r8 + rq;
        const int slot = sl ^ (row & 7);  // pre-swizzled source slot
        const char* base = isY ? (const char*)Yb + (size_t)jBase * (D_DIM * 2)
                               : (const char*)Xb + (size_t)iBase * (D_DIM * 2);
        src[c] = base + (size_t)row * (D_DIM * 2) + slot * 16;
        dst[c] = isY * (BM * BK * 2) + r8 * 128;
    }

    #pragma unroll
    for (int t = 0; t < NSTEP; ++t) {
        #pragma unroll
        for (int c = 0; c < 8; ++c)
            __builtin_amdgcn_global_load_lds(
                (const __attribute__((address_space(1))) void*)(src[c] + t * (BK * 2)),
                (__attribute__((address_space(3))) void*)(lds + dst[c]),
                16, 0, 0);
        __syncthreads();

        const char* Xs = lds;
        const char* Ys = lds + BM * BK * 2;
        #pragma unroll
        for (int kk = 0; kk < 4; ++kk) {
            // logical 16B k-slot g = kk*2 + (l>>5); physical = g ^ (row&7), row&7 == l&7
            const int sx = ((kk * 2 + (l >> 5)) ^ (l & 7)) * 16;
            const int lr = l & 31;
            bf16x8 a0 = *(const bf16x8*)(Ys + (wj * 64 +  0 + lr) * 128 + sx);
            bf16x8 a1 = *(const bf16x8*)(Ys + (wj * 64 + 32 + lr) * 128 + sx);
            bf16x8 b0 = *(const bf16x8*)(Xs + (wi * 128 +  0 + lr) * 128 + sx);
            bf16x8 b1 = *(const bf16x8*)(Xs + (wi * 128 + 32 + lr) * 128 + sx);
            bf16x8 b2 = *(const bf16x8*)(Xs + (wi * 128 + 64 + lr) * 128 + sx);
            bf16x8 b3 = *(const bf16x8*)(Xs + (wi * 128 + 96 + lr) * 128 + sx);
            acc[0][0] = __builtin_amdgcn_mfma_f32_32x32x16_bf16(a0, b0, acc[0][0], 0, 0, 0);
            acc[0][1] = __builtin_amdgcn_mfma_f32_32x32x16_bf16(a0, b1, acc[0][1], 0, 0, 0);
            acc[0][2] = __builtin_amdgcn_mfma_f32_32x32x16_bf16(a0, b2, acc[0][2], 0, 0, 0);
            acc[0][3] = __builtin_amdgcn_mfma_f32_32x32x16_bf16(a0, b3, acc[0][3], 0, 0, 0);
            acc[1][0] = __builtin_amdgcn_mfma_f32_32x32x16_bf16(a1, b0, acc[1][0], 0, 0, 0);
            acc[1][1] = __builtin_amdgcn_mfma_f32_32x32x16_bf16(a1, b1, acc[1][1], 0, 0, 0);
            acc[1][2] = __builtin_amdgcn_mfma_f32_32x32x16_bf16(a1, b2, acc[1][2], 0, 0, 0);
            acc[1][3] = __builtin_amdgcn_mfma_f32_32x32x16_bf16(a1, b3, acc[1][3], 0, 0, 0);
        }
        __syncthreads();
    }

    // ---- epilogue: rowsum_i += sum_j exp((S[i][j]-1)/tau) ----
    // D layout (32x32): n=i = lane&31; m=j = (reg&3)+8*(reg>>2)+4*(lane>>5).
    float part[4];
    #pragma unroll
    for (int fi = 0; fi < 4; ++fi) {
        float s = 0.f;
        #pragma unroll
        for (int fj = 0; fj < 2; ++fj)
            #pragma unroll
            for (int r = 0; r < 16; ++r)
                s += __expf(fmaf(acc[fj][fi][r], INV_T, -INV_T));
        s += __shfl_xor(s, 32);  // combine the two j-column-halves (lane>>5)
        part[fi] = s;
    }
    // Conflict-free combine: each wave writes its disjoint slot rowpart4[wj][row]
    // (plain stores, lanes 0..31 -> consecutive banks), then 256 threads sum 4.
    float (*rowpart4)[BM] = (float (*)[BM])lds;  // 4 KB, LDS free after last barrier
    if (l < 32) {
        #pragma unroll
        for (int fi = 0; fi < 4; ++fi)
            rowpart4[wj][wi * 128 + fi * 32 + l] = part[fi];
    }
    __syncthreads();
    if (tid < BM) {
        const float v = rowpart4[0][tid] + rowpart4[1][tid]
                      + rowpart4[2][tid] + rowpart4[3][tid];
        atomicAdd(&rowsum[iBase + tid], v);
    }
}

// ---------------------------------------------------------------------------
// Kernel C1: per-row loss terms, block-reduced, one atomic per block.
// ---------------------------------------------------------------------------
__global__ __launch_bounds__(256) void lit_partial(
    const float* __restrict__ Sv, const float* __restrict__ rowsum,
    float* __restrict__ acc1)
{
    const int i = blockIdx.x * 256 + threadIdx.x;
    float v = Sv[i] - logf(rowsum[i]);
    #pragma unroll
    for (int o = 1; o < 64; o <<= 1) v += __shfl_xor(v, o);
    __shared__ float sred[4];
    if ((threadIdx.x & 63) == 0) sred[threadIdx.x >> 6] = v;
    __syncthreads();
    if (threadIdx.x == 0)
        atomicAdd(acc1, sred[0] + sred[1] + sred[2] + sred[3]);
}

// Kernel C2: scalar finalize.
__global__ void lit_final(const float* __restrict__ acc1, float* __restrict__ out, int N)
{
    out[0] = -acc1[0] / (float)N;
}

// ---------------------------------------------------------------------------
extern "C" void kernel_launch(void* const* d_in, const int* in_sizes, int n_in,
                              void* d_out, int out_size, void* d_ws, size_t ws_size,
                              hipStream_t stream)
{
    const float* X = (const float*)d_in[0];
    const float* Y = (const float*)d_in[1];
    const int N = in_sizes[0] / D_DIM;  // 16384

    char* ws = (char*)d_ws;
    __hip_bfloat16* Xb = (__hip_bfloat16*)ws;
    __hip_bfloat16* Yb = (__hip_bfloat16*)(ws + (size_t)N * D_DIM * 2);
    float* Sv     = (float*)(ws + (size_t)N * D_DIM * 4);
    float* rowsum = (float*)(ws + (size_t)N * D_DIM * 4 + (size_t)N * 4);
    float* acc1   = (float*)(ws + (size_t)N * D_DIM * 4 + (size_t)N * 8);

    lit_normalize<<<N / 4, 256, 0, stream>>>(X, Y, Xb, Yb, Sv, rowsum, acc1);
    dim3 grid(N / BN, N / BM);
    lit_gemm_rowsum<<<grid, 512, 0, stream>>>(Xb, Yb, rowsum);
    lit_partial<<<N / 256, 256, 0, stream>>>(Sv, rowsum, acc1);
    lit_final<<<1, 1, 0, stream>>>(acc1, (float*)d_out, N);
}